// Round 2
// baseline (2141.167 us; speedup 1.0000x reference)
//
#include <hip/hip_runtime.h>
#include <hip/hip_bf16.h>

#define E_N 100000
#define N_N 50000
#define D_N 256
#define H_N 4
#define R_N 4
#define TD_N 64
#define ADIM 576

// ---------------------------------------------------------------------------
// kdetect: decide whether target_index arrived as int64 (JAX x64 on) or int32.
// For int64 with values < 2^31, every odd 32-bit word is 0. Probability that
// 64 genuine int32 targets are all 0 is (1/50000)^64 ~ 0.
__global__ void kdetect(const int* __restrict__ tgt, unsigned* __restrict__ flagp) {
    int t = threadIdx.x;                       // 64 threads, 1 wave
    int v = tgt[2 * t + 1];                    // index <= 127 < E, safe either way
    unsigned long long m = __ballot(v != 0);
    if (t == 0) flagp[0] = (m == 0ull) ? 1u : 0u;   // 1 = int64 layout
}

// ---------------------------------------------------------------------------
// k0: fold attention vectors through W:
//   aW1[r][h][i] = sum_d a[r][h][d]     * W[r][d][i]
//   aW2[r][h][i] = sum_d a[r][h][D+d]   * W[r][d][i]
//   ab[r][h]     = sum_i (a1[i]+a2[i])  * b[r][i]
__global__ void k0_precomp(const float* __restrict__ a, const float* __restrict__ W,
                           const float* __restrict__ b, float* __restrict__ aW1,
                           float* __restrict__ aW2, float* __restrict__ ab) {
    int t = blockIdx.x * 256 + threadIdx.x;    // 4096 threads total
    int i = t & 255, rh = t >> 8;
    int r = rh >> 2;
    const float* arow = a + (size_t)rh * ADIM;
    const float* wr   = W + (size_t)r * (D_N * D_N);
    float s1 = 0.f, s2 = 0.f;
    for (int d = 0; d < D_N; ++d) {
        float wv = wr[d * D_N + i];            // column read, coalesced across i
        s1 += arow[d] * wv;
        s2 += arow[D_N + d] * wv;
    }
    aW1[rh * D_N + i] = s1;
    aW2[rh * D_N + i] = s2;
    if (i == 0) {
        float sb = 0.f;
        for (int j = 0; j < D_N; ++j) sb += (arow[j] + arow[D_N + j]) * b[r * D_N + j];
        ab[rh] = sb;
    }
}

// ---------------------------------------------------------------------------
// k1: one wave per edge. logit[h] = leaky_relu(aW1.h_v + aW2.h_u + a3.phi + ab)
// expl[e][h] = exp(logit) (no max subtraction needed: logits bounded ~ +-6),
// atomically accumulate denom[(n,r,h)], plus per-relation histogram.
__global__ __launch_bounds__(256) void k1_logits(
    const float* __restrict__ hv, const float* __restrict__ hu,
    const int* __restrict__ rel, const float* __restrict__ dt,
    const int* __restrict__ tgt, const float* __restrict__ a,
    const float* __restrict__ tw, const float* __restrict__ aW1,
    const float* __restrict__ aW2, const float* __restrict__ ab,
    float* __restrict__ expl, float* __restrict__ denomv,
    unsigned* __restrict__ counts, const unsigned* __restrict__ flagp)
{
    __shared__ unsigned hist[R_N];
    int t = threadIdx.x;
    if (t < R_N) hist[t] = 0;
    __syncthreads();

    int lane = t & 63;
    int e = blockIdx.x * 4 + (t >> 6);         // grid sized exactly: E/4 blocks
    int r = rel[e];
    int n = flagp[0] ? tgt[2 * (size_t)e] : tgt[e];

    float4 xv = *(const float4*)(hv + (size_t)e * D_N + lane * 4);
    float4 xu = *(const float4*)(hu + (size_t)e * D_N + lane * 4);
    float cph = cosf(dt[e] * tw[lane]);        // lane <-> time dim (TD == 64)

    float accs[4];
    #pragma unroll
    for (int h = 0; h < H_N; ++h) {
        const float* w1 = aW1 + (size_t)(r * H_N + h) * D_N + lane * 4;
        const float* w2 = aW2 + (size_t)(r * H_N + h) * D_N + lane * 4;
        float4 c1 = *(const float4*)w1;
        float4 c2 = *(const float4*)w2;
        float s = c1.x * xv.x + c1.y * xv.y + c1.z * xv.z + c1.w * xv.w
                + c2.x * xu.x + c2.y * xu.y + c2.z * xu.z + c2.w * xu.w;
        s += a[(size_t)(r * H_N + h) * ADIM + 2 * D_N + lane] * cph;
        accs[h] = s;
    }
    #pragma unroll
    for (int m = 1; m < 64; m <<= 1) {
        accs[0] += __shfl_xor(accs[0], m, 64);
        accs[1] += __shfl_xor(accs[1], m, 64);
        accs[2] += __shfl_xor(accs[2], m, 64);
        accs[3] += __shfl_xor(accs[3], m, 64);
    }
    if (lane < H_N) {
        float v = (lane == 0) ? accs[0] : (lane == 1) ? accs[1]
                : (lane == 2) ? accs[2] : accs[3];           // static select (no scratch)
        v += ab[r * H_N + lane];
        v = (v > 0.f) ? v : 0.2f * v;                        // leaky_relu
        float ex = expf(v);
        expl[(size_t)e * H_N + lane] = ex;
        atomicAdd(denomv + (size_t)n * (R_N * H_N) + r * H_N + lane, ex);
    }
    if (lane == 0) atomicAdd(&hist[r], 1u);
    __syncthreads();
    if (t < R_N) atomicAdd(counts + t, hist[t]);
}

// ---------------------------------------------------------------------------
// k2: bucket starts (exclusive scan of 4 counts) -> cursors
__global__ void k2_scan(const unsigned* __restrict__ counts, unsigned* __restrict__ cursors) {
    if (threadIdx.x == 0 && blockIdx.x == 0) {
        unsigned s = 0;
        for (int r = 0; r < R_N; ++r) { cursors[r] = s; s += counts[r]; }
    }
}

// ---------------------------------------------------------------------------
// k3: two-level scatter of edge ids into relation buckets (sorted by relation)
__global__ __launch_bounds__(256) void k3_scatter(
    const int* __restrict__ rel, unsigned* __restrict__ cursors, unsigned* __restrict__ bucket)
{
    __shared__ unsigned lcnt[R_N], lbase[R_N];
    int t = threadIdx.x;
    int e = blockIdx.x * 256 + t;
    if (t < R_N) lcnt[t] = 0;
    __syncthreads();
    int r = 0; unsigned lpos = 0;
    bool valid = (e < E_N);
    if (valid) { r = rel[e]; lpos = atomicAdd(&lcnt[r], 1u); }
    __syncthreads();
    if (t < R_N) lbase[t] = atomicAdd(cursors + t, lcnt[t]);
    __syncthreads();
    if (valid) bucket[lbase[r] + lpos] = (unsigned)e;
}

// ---------------------------------------------------------------------------
// k4: message GEMM + softmax scale + scatter.
// Block: 64 edges (one relation, from bucket) x 256 d. 256 threads,
// per-thread 8e x 8d micro-tile, k-tiles of 32 staged in LDS.
// Bbuf rows are 128 B (= one bank cycle) so d-parallel reads would all hit the
// same 16B bank group -> XOR-swizzle the f4 slot with (d>>3)&7 (T2 pattern).
__global__ __launch_bounds__(256) void k4_msg(
    const float* __restrict__ hu, const int* __restrict__ rel,
    const int* __restrict__ tgt, const float* __restrict__ W,
    const float* __restrict__ bb, const float* __restrict__ expl,
    const float* __restrict__ denomv, const unsigned* __restrict__ bucket,
    const unsigned* __restrict__ flagp, float* __restrict__ out)
{
    __shared__ float Abuf[64 * 32];       // hu tile   [e][k], rows 128B, no swizzle
    __shared__ float Bbuf[256 * 32];      // W[rs] tile [d][k], f4-slot XOR swizzle
    __shared__ unsigned eids[64];
    __shared__ int rl[64];
    __shared__ int tg[64];

    int t = threadIdx.x;
    if (t < 64) {
        int ge = blockIdx.x * 64 + t;
        if (ge >= E_N) ge = E_N - 1;      // duplicate tail edge; guarded in epilogue
        unsigned e = bucket[ge];
        eids[t] = e;
        rl[t] = rel[e];
        tg[t] = flagp[0] ? tgt[2 * (size_t)e] : tgt[e];
    }
    __syncthreads();

    int r0 = rl[0], r1 = rl[63];          // sorted: uniform blocks do 1 pass
    int td = t & 31, te = t >> 5;         // d-block = td*8..+7, e-block = te*8..+7

    for (int rs = r0; rs <= r1; ++rs) {
        float acc[8][8] = {};
        #pragma unroll 1
        for (int kt = 0; kt < 8; ++kt) {
            __syncthreads();
            {   // stage A: 512 f4, 2 per thread, coalesced 128B per 8 lanes
                int j = t;
                #pragma unroll
                for (int rep = 0; rep < 2; ++rep) {
                    int e = j >> 3, c = j & 7;
                    float4 v = *(const float4*)(hu + (size_t)eids[e] * D_N + kt * 32 + c * 4);
                    *(float4*)(Abuf + (e * 8 + c) * 4) = v;
                    j += 256;
                }
            }
            {   // stage B: 2048 f4, 8 per thread, swizzled slot
                int j = t;
                #pragma unroll
                for (int rep = 0; rep < 8; ++rep) {
                    int d = j >> 3, c = j & 7;
                    float4 v = *(const float4*)(W + (size_t)rs * (D_N * D_N) + d * D_N + kt * 32 + c * 4);
                    *(float4*)(Bbuf + (d * 8 + (c ^ ((d >> 3) & 7))) * 4) = v;
                    j += 256;
                }
            }
            __syncthreads();
            #pragma unroll 1
            for (int k4 = 0; k4 < 8; ++k4) {
                float4 af[8];
                #pragma unroll
                for (int i = 0; i < 8; ++i)
                    af[i] = *(const float4*)(Abuf + ((te * 8 + i) * 8 + k4) * 4); // broadcast-pair
                int k4s = k4 ^ (td & 7);  // per-thread constant swizzle
                #pragma unroll
                for (int j = 0; j < 8; ++j) {
                    float4 b4 = *(const float4*)(Bbuf + ((td * 8 + j) * 8 + k4s) * 4);
                    #pragma unroll
                    for (int i = 0; i < 8; ++i)
                        acc[i][j] += af[i].x * b4.x + af[i].y * b4.y
                                   + af[i].z * b4.z + af[i].w * b4.w;
                }
            }
        }
        // epilogue: bias + alpha + atomic scatter. Fully unrolled (static acc idx).
        int h = td >> 3;                  // d = td*8+j all within one 64-chunk
        #pragma unroll
        for (int i = 0; i < 8; ++i) {
            int ee = te * 8 + i;
            if (blockIdx.x * 64 + ee < E_N && rl[ee] == rs) {
                unsigned eid = eids[ee];
                int n = tg[ee];
                float al = expl[(size_t)eid * H_N + h]
                         / (denomv[(size_t)n * (R_N * H_N) + rs * H_N + h] + 1e-9f);
                #pragma unroll
                for (int j = 0; j < 8; ++j) {
                    float wu = acc[i][j] + bb[rs * D_N + td * 8 + j];
                    atomicAdd(out + (size_t)n * D_N + td * 8 + j, al * wu);
                }
            }
        }
    }
}

// ---------------------------------------------------------------------------
extern "C" void kernel_launch(void* const* d_in, const int* in_sizes, int n_in,
                              void* d_out, int out_size, void* d_ws, size_t ws_size,
                              hipStream_t stream) {
    const float* hv  = (const float*)d_in[0];
    const float* hu  = (const float*)d_in[1];
    const int*   rel = (const int*)d_in[2];
    const float* dt  = (const float*)d_in[3];
    const int*   tgt = (const int*)d_in[4];
    // d_in[5] = num_nodes (scalar) -- unused, N hardcoded
    const float* W   = (const float*)d_in[6];
    const float* b   = (const float*)d_in[7];
    const float* a   = (const float*)d_in[8];
    const float* tw  = (const float*)d_in[9];
    float* out = (float*)d_out;

    // workspace layout (floats)
    float* ws_f   = (float*)d_ws;
    float* expl   = ws_f;                       // E*H           = 400000
    float* denomv = ws_f + 400000;              // N*R*H         = 800000
    float* aW1    = ws_f + 1200000;             // R*H*D         = 4096
    float* aW2    = ws_f + 1204096;             // 4096
    float* ab     = ws_f + 1208192;             // 16
    unsigned* counts  = (unsigned*)(ws_f + 1208208);  // 4
    unsigned* cursors = counts + 4;                   // 4
    unsigned* flagp   = counts + 8;                   // 1 (+pad)
    unsigned* bucket  = counts + 16;                  // E

    hipMemsetAsync(out, 0, (size_t)out_size * sizeof(float), stream);
    hipMemsetAsync(denomv, 0, (size_t)N_N * R_N * H_N * sizeof(float), stream);
    hipMemsetAsync(counts, 0, 16, stream);

    kdetect<<<1, 64, 0, stream>>>(tgt, flagp);
    k0_precomp<<<16, 256, 0, stream>>>(a, W, b, aW1, aW2, ab);
    k1_logits<<<E_N / 4, 256, 0, stream>>>(hv, hu, rel, dt, tgt, a, tw,
                                           aW1, aW2, ab, expl, denomv, counts, flagp);
    k2_scan<<<1, 64, 0, stream>>>(counts, cursors);
    k3_scatter<<<(E_N + 255) / 256, 256, 0, stream>>>(rel, cursors, bucket);
    k4_msg<<<(E_N + 63) / 64, 256, 0, stream>>>(hu, rel, tgt, W, b,
                                                expl, denomv, bucket, flagp, out);
}

// Round 12
// 560.389 us; speedup vs baseline: 3.8209x; 3.8209x over previous
//
#include <hip/hip_runtime.h>
#include <hip/hip_bf16.h>

#define E_N 100000
#define N_N 50000
#define D_N 256
#define H_N 4
#define R_N 4
#define TD_N 64
#define ADIM 576
#define NCHUNK 196   // ceil(N/256) for the 2-level node scan

// ---------------------------------------------------------------------------
// kdetect: decide whether target_index arrived as int64 (JAX x64 on) or int32.
__global__ void kdetect(const int* __restrict__ tgt, unsigned* __restrict__ flagp) {
    int t = threadIdx.x;
    int v = tgt[2 * t + 1];
    unsigned long long m = __ballot(v != 0);
    if (t == 0) flagp[0] = (m == 0ull) ? 1u : 0u;   // 1 = int64 layout
}

__device__ __forceinline__ int load_tgt(const int* tgt, unsigned flag, int e) {
    return flag ? tgt[2 * (size_t)e] : tgt[e];
}

// ---------------------------------------------------------------------------
// k0: fold attention vectors through W (see round-0 derivation).
__global__ void k0_precomp(const float* __restrict__ a, const float* __restrict__ W,
                           const float* __restrict__ b, float* __restrict__ aW1,
                           float* __restrict__ aW2, float* __restrict__ ab) {
    int t = blockIdx.x * 256 + threadIdx.x;
    int i = t & 255, rh = t >> 8;
    int r = rh >> 2;
    const float* arow = a + (size_t)rh * ADIM;
    const float* wr   = W + (size_t)r * (D_N * D_N);
    float s1 = 0.f, s2 = 0.f;
    for (int d = 0; d < D_N; ++d) {
        float wv = wr[d * D_N + i];
        s1 += arow[d] * wv;
        s2 += arow[D_N + d] * wv;
    }
    aW1[rh * D_N + i] = s1;
    aW2[rh * D_N + i] = s2;
    if (i == 0) {
        float sb = 0.f;
        for (int j = 0; j < D_N; ++j) sb += (arow[j] + arow[D_N + j]) * b[r * D_N + j];
        ab[rh] = sb;
    }
}

// ---------------------------------------------------------------------------
// k1: one wave per edge; logits + exp + denom atomics. NO histogram here
// (round-2 post-mortem: 100K atomics to one line serialized the grid).
__global__ __launch_bounds__(256) void k1_logits(
    const float* __restrict__ hv, const float* __restrict__ hu,
    const int* __restrict__ rel, const float* __restrict__ dt,
    const int* __restrict__ tgt, const float* __restrict__ a,
    const float* __restrict__ tw, const float* __restrict__ aW1,
    const float* __restrict__ aW2, const float* __restrict__ ab,
    float* __restrict__ expl, float* __restrict__ denomv,
    const unsigned* __restrict__ flagp)
{
    int t = threadIdx.x;
    int lane = t & 63;
    int e = blockIdx.x * 4 + (t >> 6);
    int r = rel[e];
    int n = load_tgt(tgt, flagp[0], e);

    float4 xv = *(const float4*)(hv + (size_t)e * D_N + lane * 4);
    float4 xu = *(const float4*)(hu + (size_t)e * D_N + lane * 4);
    float cph = cosf(dt[e] * tw[lane]);

    float accs[4];
    #pragma unroll
    for (int h = 0; h < H_N; ++h) {
        const float* w1 = aW1 + (size_t)(r * H_N + h) * D_N + lane * 4;
        const float* w2 = aW2 + (size_t)(r * H_N + h) * D_N + lane * 4;
        float4 c1 = *(const float4*)w1;
        float4 c2 = *(const float4*)w2;
        float s = c1.x * xv.x + c1.y * xv.y + c1.z * xv.z + c1.w * xv.w
                + c2.x * xu.x + c2.y * xu.y + c2.z * xu.z + c2.w * xu.w;
        s += a[(size_t)(r * H_N + h) * ADIM + 2 * D_N + lane] * cph;
        accs[h] = s;
    }
    #pragma unroll
    for (int m = 1; m < 64; m <<= 1) {
        accs[0] += __shfl_xor(accs[0], m, 64);
        accs[1] += __shfl_xor(accs[1], m, 64);
        accs[2] += __shfl_xor(accs[2], m, 64);
        accs[3] += __shfl_xor(accs[3], m, 64);
    }
    if (lane < H_N) {
        float v = (lane == 0) ? accs[0] : (lane == 1) ? accs[1]
                : (lane == 2) ? accs[2] : accs[3];
        v += ab[r * H_N + lane];
        v = (v > 0.f) ? v : 0.2f * v;
        float ex = expf(v);
        expl[(size_t)e * H_N + lane] = ex;
        atomicAdd(denomv + (size_t)n * (R_N * H_N) + r * H_N + lane, ex);
    }
}

// ---------------------------------------------------------------------------
// khist: relation histogram (LDS, 1024 global atomics total) + node degrees
// (scattered atomics over 50K cells — low contention).
__global__ __launch_bounds__(256) void khist(
    const int* __restrict__ rel, const int* __restrict__ tgt,
    const unsigned* __restrict__ flagp, unsigned* __restrict__ counts,
    unsigned* __restrict__ deg)
{
    __shared__ unsigned lc[R_N];
    int t = threadIdx.x;
    if (t < R_N) lc[t] = 0;
    __syncthreads();
    unsigned flag = flagp[0];
    for (int e = blockIdx.x * 256 + t; e < E_N; e += 256 * 256) {
        atomicAdd(&lc[rel[e]], 1u);
        atomicAdd(&deg[load_tgt(tgt, flag, e)], 1u);
    }
    __syncthreads();
    if (t < R_N) atomicAdd(counts + t, lc[t]);
}

// ---------------------------------------------------------------------------
// k2: relation bucket starts
__global__ void k2_scan(const unsigned* __restrict__ counts, unsigned* __restrict__ cursors) {
    if (threadIdx.x == 0 && blockIdx.x == 0) {
        unsigned s = 0;
        for (int r = 0; r < R_N; ++r) { cursors[r] = s; s += counts[r]; }
    }
}

// ---------------------------------------------------------------------------
// k3: scatter edge ids into relation buckets
__global__ __launch_bounds__(256) void k3_scatter(
    const int* __restrict__ rel, unsigned* __restrict__ cursors, unsigned* __restrict__ bucket)
{
    __shared__ unsigned lcnt[R_N], lbase[R_N];
    int t = threadIdx.x;
    int e = blockIdx.x * 256 + t;
    if (t < R_N) lcnt[t] = 0;
    __syncthreads();
    int r = 0; unsigned lpos = 0;
    bool valid = (e < E_N);
    if (valid) { r = rel[e]; lpos = atomicAdd(&lcnt[r], 1u); }
    __syncthreads();
    if (t < R_N) lbase[t] = atomicAdd(cursors + t, lcnt[t]);
    __syncthreads();
    if (valid) bucket[lbase[r] + lpos] = (unsigned)e;
}

// ---------------------------------------------------------------------------
// node-offset scan (2-level): A) per-chunk sums, B) scan of 256 chunk sums,
// C) per-chunk sequential scan -> nodeoff + ncur copies.
__global__ __launch_bounds__(256) void kscanA(const unsigned* __restrict__ deg,
                                              unsigned* __restrict__ bsum) {
    __shared__ unsigned red[256];
    int b = blockIdx.x, t = threadIdx.x;
    int idx = b * NCHUNK + t;
    red[t] = (t < NCHUNK && idx < N_N) ? deg[idx] : 0u;
    __syncthreads();
    for (int off = 128; off > 0; off >>= 1) {
        if (t < off) red[t] += red[t + off];
        __syncthreads();
    }
    if (t == 0) bsum[b] = red[0];
}

__global__ void kscanB(const unsigned* __restrict__ bsum, unsigned* __restrict__ boff) {
    __shared__ unsigned s[256];
    int t = threadIdx.x;
    unsigned v = bsum[t];
    s[t] = v;
    __syncthreads();
    for (int off = 1; off < 256; off <<= 1) {
        unsigned add = (t >= off) ? s[t - off] : 0u;
        __syncthreads();
        s[t] += add;
        __syncthreads();
    }
    boff[t] = s[t] - v;   // exclusive
}

__global__ __launch_bounds__(256) void kscanC(const unsigned* __restrict__ deg,
                                              const unsigned* __restrict__ boff,
                                              unsigned* __restrict__ nodeoff,
                                              unsigned* __restrict__ ncur) {
    __shared__ unsigned d[NCHUNK], o[NCHUNK];
    int b = blockIdx.x, t = threadIdx.x;
    int base = b * NCHUNK;
    if (t < NCHUNK && base + t < N_N) d[t] = deg[base + t];
    __syncthreads();
    if (t == 0) {
        unsigned run = boff[b];
        int lim = N_N - base; if (lim > NCHUNK) lim = NCHUNK;
        for (int i = 0; i < lim; ++i) { o[i] = run; run += d[i]; }
    }
    __syncthreads();
    if (t < NCHUNK && base + t < N_N) {
        nodeoff[base + t] = o[t];
        ncur[base + t] = o[t];
    }
}

__global__ __launch_bounds__(256) void kscat2(
    const int* __restrict__ tgt, const unsigned* __restrict__ flagp,
    unsigned* __restrict__ ncur, unsigned* __restrict__ tlist)
{
    int e = blockIdx.x * 256 + threadIdx.x;
    if (e < E_N) {
        int n = load_tgt(tgt, flagp[0], e);
        unsigned pos = atomicAdd(&ncur[n], 1u);
        tlist[pos] = (unsigned)e;
    }
}

// ---------------------------------------------------------------------------
// k4: message GEMM (relation-bucketed 64e x 256d tile, 8x8 microtile).
// GATHER=1: plain float4 stores of alpha*(W h_u + b) into msg[e][d].
// GATHER=0: fallback atomic scatter directly into out.
template <int GATHER>
__global__ __launch_bounds__(256) void k4_msg(
    const float* __restrict__ hu, const int* __restrict__ rel,
    const int* __restrict__ tgt, const float* __restrict__ W,
    const float* __restrict__ bb, const float* __restrict__ expl,
    const float* __restrict__ denomv, const unsigned* __restrict__ bucket,
    const unsigned* __restrict__ flagp, float* __restrict__ msg,
    float* __restrict__ out)
{
    __shared__ float Abuf[64 * 32];       // hu tile   [e][k]
    __shared__ float Bbuf[256 * 32];      // W[rs] tile [d][k], f4-slot XOR swizzle
    __shared__ unsigned eids[64];
    __shared__ int rl[64];
    __shared__ int tg[64];

    int t = threadIdx.x;
    if (t < 64) {
        int ge = blockIdx.x * 64 + t;
        if (ge >= E_N) ge = E_N - 1;
        unsigned e = bucket[ge];
        eids[t] = e;
        rl[t] = rel[e];
        tg[t] = load_tgt(tgt, flagp[0], (int)e);
    }
    __syncthreads();

    int r0 = rl[0], r1 = rl[63];
    int td = t & 31, te = t >> 5;

    for (int rs = r0; rs <= r1; ++rs) {
        float acc[8][8] = {};
        #pragma unroll 1
        for (int kt = 0; kt < 8; ++kt) {
            __syncthreads();
            {   // stage A
                int j = t;
                #pragma unroll
                for (int rep = 0; rep < 2; ++rep) {
                    int e = j >> 3, c = j & 7;
                    float4 v = *(const float4*)(hu + (size_t)eids[e] * D_N + kt * 32 + c * 4);
                    *(float4*)(Abuf + (e * 8 + c) * 4) = v;
                    j += 256;
                }
            }
            {   // stage B (swizzled)
                int j = t;
                #pragma unroll
                for (int rep = 0; rep < 8; ++rep) {
                    int d = j >> 3, c = j & 7;
                    float4 v = *(const float4*)(W + (size_t)rs * (D_N * D_N) + d * D_N + kt * 32 + c * 4);
                    *(float4*)(Bbuf + (d * 8 + (c ^ ((d >> 3) & 7))) * 4) = v;
                    j += 256;
                }
            }
            __syncthreads();
            #pragma unroll 1
            for (int k4 = 0; k4 < 8; ++k4) {
                float4 af[8];
                #pragma unroll
                for (int i = 0; i < 8; ++i)
                    af[i] = *(const float4*)(Abuf + ((te * 8 + i) * 8 + k4) * 4);
                int k4s = k4 ^ (td & 7);
                #pragma unroll
                for (int j = 0; j < 8; ++j) {
                    float4 b4 = *(const float4*)(Bbuf + ((td * 8 + j) * 8 + k4s) * 4);
                    #pragma unroll
                    for (int i = 0; i < 8; ++i)
                        acc[i][j] += af[i].x * b4.x + af[i].y * b4.y
                                   + af[i].z * b4.z + af[i].w * b4.w;
                }
            }
        }
        int h = td >> 3;
        #pragma unroll
        for (int i = 0; i < 8; ++i) {
            int ee = te * 8 + i;
            if (blockIdx.x * 64 + ee < E_N && rl[ee] == rs) {
                unsigned eid = eids[ee];
                int n = tg[ee];
                float al = expl[(size_t)eid * H_N + h]
                         / (denomv[(size_t)n * (R_N * H_N) + rs * H_N + h] + 1e-9f);
                if (GATHER) {
                    float4 v0, v1;
                    v0.x = al * (acc[i][0] + bb[rs * D_N + td * 8 + 0]);
                    v0.y = al * (acc[i][1] + bb[rs * D_N + td * 8 + 1]);
                    v0.z = al * (acc[i][2] + bb[rs * D_N + td * 8 + 2]);
                    v0.w = al * (acc[i][3] + bb[rs * D_N + td * 8 + 3]);
                    v1.x = al * (acc[i][4] + bb[rs * D_N + td * 8 + 4]);
                    v1.y = al * (acc[i][5] + bb[rs * D_N + td * 8 + 5]);
                    v1.z = al * (acc[i][6] + bb[rs * D_N + td * 8 + 6]);
                    v1.w = al * (acc[i][7] + bb[rs * D_N + td * 8 + 7]);
                    *(float4*)(msg + (size_t)eid * D_N + td * 8)     = v0;
                    *(float4*)(msg + (size_t)eid * D_N + td * 8 + 4) = v1;
                } else {
                    #pragma unroll
                    for (int j = 0; j < 8; ++j) {
                        float wu = acc[i][j] + bb[rs * D_N + td * 8 + j];
                        atomicAdd(out + (size_t)n * D_N + td * 8 + j, al * wu);
                    }
                }
            }
        }
    }
}

// ---------------------------------------------------------------------------
// k7: per-node gather-reduce of messages (no atomics). One wave per node.
__global__ __launch_bounds__(256) void k7_gather(
    const float* __restrict__ msg, const unsigned* __restrict__ tlist,
    const unsigned* __restrict__ nodeoff, const unsigned* __restrict__ deg,
    float* __restrict__ out)
{
    int t = threadIdx.x;
    int lane = t & 63;
    int n = blockIdx.x * 4 + (t >> 6);
    if (n >= N_N) return;
    unsigned s = nodeoff[n], c = deg[n];
    float4 acc = {0.f, 0.f, 0.f, 0.f};
    for (unsigned j = 0; j < c; ++j) {
        unsigned e = tlist[s + j];
        float4 v = *(const float4*)(msg + (size_t)e * D_N + lane * 4);
        acc.x += v.x; acc.y += v.y; acc.z += v.z; acc.w += v.w;
    }
    *(float4*)(out + (size_t)n * D_N + lane * 4) = acc;
}

// ---------------------------------------------------------------------------
extern "C" void kernel_launch(void* const* d_in, const int* in_sizes, int n_in,
                              void* d_out, int out_size, void* d_ws, size_t ws_size,
                              hipStream_t stream) {
    const float* hv  = (const float*)d_in[0];
    const float* hu  = (const float*)d_in[1];
    const int*   rel = (const int*)d_in[2];
    const float* dt  = (const float*)d_in[3];
    const int*   tgt = (const int*)d_in[4];
    const float* W   = (const float*)d_in[6];
    const float* b   = (const float*)d_in[7];
    const float* a   = (const float*)d_in[8];
    const float* tw  = (const float*)d_in[9];
    float* out = (float*)d_out;

    // workspace layout (float offsets)
    float* ws_f   = (float*)d_ws;
    float* expl   = ws_f;                        // 400000
    float* denomv = ws_f + 400000;               // 800000
    float* aW1    = ws_f + 1200000;              // 4096
    float* aW2    = ws_f + 1204096;              // 4096
    float* ab     = ws_f + 1208192;              // 16
    unsigned* counts  = (unsigned*)(ws_f + 1208208);  // 4
    unsigned* cursors = counts + 4;                   // 4
    unsigned* flagp   = counts + 8;                   // 1 (+7 pad)
    unsigned* bucket  = (unsigned*)(ws_f + 1208224);  // 100000
    unsigned* deg     = (unsigned*)(ws_f + 1308224);  // 50176
    unsigned* nodeoff = (unsigned*)(ws_f + 1358400);  // 50176
    unsigned* ncur    = (unsigned*)(ws_f + 1408576);  // 50176
    unsigned* bsum    = (unsigned*)(ws_f + 1458752);  // 256
    unsigned* boff    = (unsigned*)(ws_f + 1459008);  // 256
    unsigned* tlist   = (unsigned*)(ws_f + 1459264);  // 100000
    float* msg        = ws_f + 1559296;               // E*D = 25600000
    const size_t NEED = (size_t)(1559296 + 25600000) * 4;   // ~108.6 MB
    const bool gather = (ws_size >= NEED);

    hipMemsetAsync(denomv, 0, (size_t)N_N * R_N * H_N * sizeof(float), stream);
    hipMemsetAsync(counts, 0, 16, stream);
    if (gather) {
        hipMemsetAsync(deg, 0, 50176 * sizeof(unsigned), stream);
    } else {
        hipMemsetAsync(out, 0, (size_t)out_size * sizeof(float), stream);
    }

    kdetect<<<1, 64, 0, stream>>>(tgt, flagp);
    k0_precomp<<<16, 256, 0, stream>>>(a, W, b, aW1, aW2, ab);
    k1_logits<<<E_N / 4, 256, 0, stream>>>(hv, hu, rel, dt, tgt, a, tw,
                                           aW1, aW2, ab, expl, denomv, flagp);
    if (gather) {
        khist<<<256, 256, 0, stream>>>(rel, tgt, flagp, counts, deg);
    } else {
        khist<<<256, 256, 0, stream>>>(rel, tgt, flagp, counts, ncur /*dummy sink*/);
    }
    k2_scan<<<1, 64, 0, stream>>>(counts, cursors);
    k3_scatter<<<(E_N + 255) / 256, 256, 0, stream>>>(rel, cursors, bucket);

    if (gather) {
        kscanA<<<256, 256, 0, stream>>>(deg, bsum);
        kscanB<<<1, 256, 0, stream>>>(bsum, boff);
        kscanC<<<256, 256, 0, stream>>>(deg, boff, nodeoff, ncur);
        kscat2<<<(E_N + 255) / 256, 256, 0, stream>>>(tgt, flagp, ncur, tlist);
        k4_msg<1><<<(E_N + 63) / 64, 256, 0, stream>>>(hu, rel, tgt, W, b,
                                                       expl, denomv, bucket, flagp, msg, out);
        k7_gather<<<(N_N + 3) / 4, 256, 0, stream>>>(msg, tlist, nodeoff, deg, out);
    } else {
        k4_msg<0><<<(E_N + 63) / 64, 256, 0, stream>>>(hu, rel, tgt, W, b,
                                                       expl, denomv, bucket, flagp, msg, out);
    }
}